// Round 4
// baseline (593.594 us; speedup 1.0000x reference)
//
#include <hip/hip_runtime.h>

// ---------------------------------------------------------------------------
// ExpandHarmonics: ragged expansion of reflections into Laue harmonics.
//   g      = gcd(h,k,l)
//   n_max  = floor(dHKL*g / dmin)
//   row i emits entries n = 1..n_max[i], compacted row-major.
// Outputs concatenated flat (promoted to float32):
//   [0,3M)     hkl_out   = (hkl/g)*n
//   [3M,4M)    dHKL_out  = (dHKL*g)/n
//   [4M,5M)    wl_out    = (wl*g)/n
//   [5M,37M)   meta_out  = meta[row]   (DMETA=32)
// M = out_size / 37 (harness-known total).
//
// R4/R5/R6: ROW-PUSH FULL FUSION (resubmit; broker timeouts, never measured).
//   Evidence (R1 counters): top-5 dispatches are all harness poison fills
//   (1.265 GB @ ~6.5 TB/s = ~195 us each); none of our kernels exceeds
//   193 us; by elimination our 3 kernels summed to ~130 us and ~390 us of
//   dur_us is harness-constant fill. Only lever: shrink OUR ~130 us toward
//   the ~70 us traffic floor.
//   - k_out + pack array eliminated. k_fused writes all 4 output streams
//     directly from the expand loop: each thread owns disjoint output
//     slice [base, base+nm). Meta read EXACTLY once (was ~1.9x gather),
//     no pack write/re-read, no hkl/dHKL/wl gathers.
//   - meta copies: nt float4 loads; stores via vec4/vec2/scalar path
//     selected by the (uniform) alignment phase of 5M dwords.
//   - small streams (hkl/dHKL/wl) use plain stores -> L2 write-combining
//     handles the short per-thread runs.
//   Traffic: k_count 16 MB read; k_fused 148 MB read + 300 MB write.
//   Predicted dur: ~465 us total (390 harness + ~75 ours).
// ---------------------------------------------------------------------------

typedef float f32x4 __attribute__((ext_vector_type(4)));
typedef float f32x2 __attribute__((ext_vector_type(2)));

__device__ __forceinline__ int gcd2(int a, int b) {
    while (b) { int t = a % b; a = b; b = t; }
    return a;
}
__device__ __forceinline__ int gcd3(int a, int b, int c) {
    return gcd2(gcd2(a, b), c);
}

// n_max for row i; clamped to [0,255] (clamp only bites poisoned inputs;
// real data: g in [1,50], dHKL in [1,3) -> nm in [1,150]).
__device__ __forceinline__ int row_nmax(const int* __restrict__ hkl,
                                        const float* __restrict__ dHKL,
                                        float dmin, int i, int* g_out) {
    int h = hkl[3 * i], k = hkl[3 * i + 1], l = hkl[3 * i + 2];
    int g = gcd3(h, k, l);
    if (g < 1) g = 1;                        // poison safety
    *g_out = g;
    float d0 = dHKL[i] * (float)g;           // same f32 op order as reference
    int nm = (int)floorf(d0 / dmin);         // jnp.floor_divide(d0, dmin)
    if (nm < 0) nm = 0;                      // poison safety
    if (nm > 255) nm = 255;                  // poison safety
    return nm;
}

// K1: per-block sum of n_max
__global__ void k_count(const int* __restrict__ hkl, const float* __restrict__ dHKL,
                        const float* __restrict__ dmin_p,
                        int* __restrict__ bsums, int N) {
    int i = blockIdx.x * 256 + threadIdx.x;
    int nm = 0;
    if (i < N) {
        int g;
        nm = row_nmax(hkl, dHKL, dmin_p[0], i, &g);
    }
    __shared__ int red[256];
    red[threadIdx.x] = nm;
    __syncthreads();
    for (int s = 128; s > 0; s >>= 1) {
        if (threadIdx.x < s) red[threadIdx.x] += red[threadIdx.x + s];
        __syncthreads();
    }
    if (threadIdx.x == 0) bsums[blockIdx.x] = red[0];
}

// K2: fused expand + ALL output streams (row-push).
//   Block base = sum of bsums[0..blockIdx) (L2-resident), intra-block
//   exclusive scan for per-row base, then each thread writes its nm
//   harmonics to all four output regions directly.
__global__ void k_fused(const int* __restrict__ hkl, const float* __restrict__ dHKL,
                        const float* __restrict__ wl, const float* __restrict__ meta,
                        const float* __restrict__ dmin_p, const int* __restrict__ bsums,
                        float* __restrict__ out, int N, int M) {
    int tid = threadIdx.x;
    int i = blockIdx.x * 256 + tid;
    int nm = 0, g = 1;
    if (i < N) nm = row_nmax(hkl, dHKL, dmin_p[0], i, &g);

    __shared__ int red[256];

    // --- block base: reduce bsums[0..blockIdx.x) ---
    int acc = 0;
    for (int j = tid; j < (int)blockIdx.x; j += 256) acc += bsums[j];
    red[tid] = acc;
    __syncthreads();
    for (int s = 128; s > 0; s >>= 1) {
        if (tid < s) red[tid] += red[tid + s];
        __syncthreads();
    }
    int bb = red[0];
    __syncthreads();

    // --- intra-block exclusive scan of nm (Hillis-Steele) ---
    red[tid] = nm;
    __syncthreads();
    for (int off = 1; off < 256; off <<= 1) {
        int x = (tid >= off) ? red[tid - off] : 0;
        __syncthreads();
        red[tid] += x;
        __syncthreads();
    }
    int base = bb + red[tid] - nm;

    if (i >= N || nm <= 0) return;

    // --- per-row values ---
    int h = hkl[3 * i], k = hkl[3 * i + 1], l = hkl[3 * i + 2];
    int h0 = h / g, k0 = k / g, l0 = l / g;
    float gf = (float)g;
    float d0 = dHKL[i] * gf;                 // dHKL * g  (reference op order)
    float w0 = wl[i] * gf;                   // wl * g

    // --- meta row: read once, 16B-aligned nt loads (rows are 128 B) ---
    const f32x4* __restrict__ mrow = (const f32x4*)(meta + ((size_t)i << 5));
    f32x4 r[8];
#pragma unroll
    for (int j = 0; j < 8; j++) r[j] = __builtin_nontemporal_load(mrow + j);

    float* __restrict__ out3 = out + (size_t)3 * M;   // dHKL_out
    float* __restrict__ out4 = out + (size_t)4 * M;   // wl_out
    float* __restrict__ out5 = out + (size_t)5 * M;   // meta_out
    int phi = (int)((5u * (unsigned)M) & 3u);         // uniform alignment phase

    for (int n = 1; n <= nm; n++) {
        int m = base + n - 1;
        if ((unsigned)m >= (unsigned)M) break;        // poison safety only
        float nf = (float)n;
        // small streams: plain stores, short per-thread runs combine in L2
        out[3 * m + 0] = (float)(h0 * n);
        out[3 * m + 1] = (float)(k0 * n);
        out[3 * m + 2] = (float)(l0 * n);
        out3[m] = d0 / nf;
        out4[m] = w0 / nf;
        // meta copy: destination rows are 128 B apart, constant phase phi
        float* __restrict__ d = out5 + ((size_t)m << 5);
        if (phi == 0) {
            f32x4* __restrict__ d4 = (f32x4*)d;
#pragma unroll
            for (int j = 0; j < 8; j++) __builtin_nontemporal_store(r[j], d4 + j);
        } else if (phi == 2) {
#pragma unroll
            for (int j = 0; j < 8; j++) {
                f32x2 a = {r[j].x, r[j].y};
                f32x2 b = {r[j].z, r[j].w};
                __builtin_nontemporal_store(a, (f32x2*)(d + 4 * j));
                __builtin_nontemporal_store(b, (f32x2*)(d + 4 * j + 2));
            }
        } else {
#pragma unroll
            for (int j = 0; j < 8; j++) {
                d[4 * j + 0] = r[j].x;
                d[4 * j + 1] = r[j].y;
                d[4 * j + 2] = r[j].z;
                d[4 * j + 3] = r[j].w;
            }
        }
    }
}

extern "C" void kernel_launch(void* const* d_in, const int* in_sizes, int n_in,
                              void* d_out, int out_size, void* d_ws, size_t ws_size,
                              hipStream_t stream) {
    const int*   hkl  = (const int*)d_in[0];
    const float* dHKL = (const float*)d_in[1];
    const float* wl   = (const float*)d_in[2];
    const float* meta = (const float*)d_in[3];
    const float* dmin = (const float*)d_in[4];
    float* out = (float*)d_out;

    int N = in_sizes[0] / 3;
    int M = out_size / 37;
    if (N <= 0 || M <= 0) return;
    int nb = (N + 255) / 256;

    int* bsums = (int*)d_ws;      // [nb]

    k_count<<<nb, 256, 0, stream>>>(hkl, dHKL, dmin, bsums, N);
    k_fused<<<nb, 256, 0, stream>>>(hkl, dHKL, wl, meta, dmin, bsums, out, N, M);
}

// Round 5
// 491.787 us; speedup vs baseline: 1.2070x; 1.2070x over previous
//
#include <hip/hip_runtime.h>

// ---------------------------------------------------------------------------
// ExpandHarmonics: ragged expansion of reflections into Laue harmonics.
//   g      = gcd(h,k,l)
//   n_max  = floor(dHKL*g / dmin)
//   row i emits entries n = 1..n_max[i], compacted row-major.
// Outputs concatenated flat (promoted to float32):
//   [0,3M)     hkl_out   = (hkl/g)*n
//   [3M,4M)    dHKL_out  = (dHKL*g)/n
//   [4M,5M)    wl_out    = (wl*g)/n
//   [5M,37M)   meta_out  = meta[row]   (DMETA=32)
// M = out_size / 37 (harness-known total).
//
// R7: REVERT row-push (R4 measured 593us: k_fused 256us @ 1.9 TB/s, 24% peak,
//   VALUBusy 11% -> issue-bound on per-lane scattered 16B stores: each store
//   instruction touches 64 distinct lines (~64 TA cycles) + exec-mask
//   divergence runs max(nm)~6 iters for mean 1.8 useful).
//   Back to the R3 architecture (measured 520.9us, absmax 0.0):
//   entry-parallel consumer = unit-stride coalesced STORES, gather on the
//   LOAD side (latency-tolerant, L2-absorbed).
//   - k_count -> k_expand(inline block base, pack scatter) -> k_out(fused
//     scalar+meta block roles).
//   Polish vs R3: meta pad!=0 body path uses intra-row vector load
//   (memcpy-16) instead of 4 scalar gathers; dual-row scalar fallback only
//   when the 4-dword group straddles a row boundary (c>28).
//   Poison-hardening from R4 kept: nm clamped to [0,255] (bounds the expand
//   loop under poisoned dHKL; no-op on real data where nm<=150).
// ---------------------------------------------------------------------------

typedef float f32x4 __attribute__((ext_vector_type(4)));

__device__ __forceinline__ int gcd2(int a, int b) {
    while (b) { int t = a % b; a = b; b = t; }
    return a;
}
__device__ __forceinline__ int gcd3(int a, int b, int c) {
    return gcd2(gcd2(a, b), c);
}

// n_max for row i; clamped to [0,255] (clamp only bites poisoned inputs;
// real data: g in [1,50], dHKL in [1,3) -> nm in [1,150]).
__device__ __forceinline__ int row_nmax(const int* __restrict__ hkl,
                                        const float* __restrict__ dHKL,
                                        float dmin, int i, int* g_out) {
    int h = hkl[3 * i], k = hkl[3 * i + 1], l = hkl[3 * i + 2];
    int g = gcd3(h, k, l);
    if (g < 1) g = 1;                        // poison safety
    *g_out = g;
    float d0 = dHKL[i] * (float)g;           // same f32 op order as reference
    int nm = (int)floorf(d0 / dmin);         // jnp.floor_divide(d0, dmin)
    if (nm < 0) nm = 0;                      // poison safety
    if (nm > 255) nm = 255;                  // poison safety (bounds loop)
    return nm;
}

// K1: per-block sum of n_max
__global__ void k_count(const int* __restrict__ hkl, const float* __restrict__ dHKL,
                        const float* __restrict__ dmin_p,
                        int* __restrict__ bsums, int N) {
    int i = blockIdx.x * 256 + threadIdx.x;
    int nm = 0;
    if (i < N) {
        int g;
        nm = row_nmax(hkl, dHKL, dmin_p[0], i, &g);
    }
    __shared__ int red[256];
    red[threadIdx.x] = nm;
    __syncthreads();
    for (int s = 128; s > 0; s >>= 1) {
        if (threadIdx.x < s) red[threadIdx.x] += red[threadIdx.x + s];
        __syncthreads();
    }
    if (threadIdx.x == 0) bsums[blockIdx.x] = red[0];
}

// K2: expand. Block base = sum of bsums[0..blockIdx) computed inline
//     (bsums ~16 KB, L2-resident). Then intra-block exclusive scan of nm,
//     emit packed (row<<8 | n) descriptor per output entry.
__global__ void k_expand(const int* __restrict__ hkl, const float* __restrict__ dHKL,
                         const float* __restrict__ dmin_p, const int* __restrict__ bsums,
                         int* __restrict__ pack, int N, int M) {
    int tid = threadIdx.x;
    int i = blockIdx.x * 256 + tid;
    int nm = 0, g;
    if (i < N) nm = row_nmax(hkl, dHKL, dmin_p[0], i, &g);

    __shared__ int red[256];

    // --- block base: reduce bsums[0..blockIdx.x) ---
    int acc = 0;
    for (int j = tid; j < (int)blockIdx.x; j += 256) acc += bsums[j];
    red[tid] = acc;
    __syncthreads();
    for (int s = 128; s > 0; s >>= 1) {
        if (tid < s) red[tid] += red[tid + s];
        __syncthreads();
    }
    int bb = red[0];
    __syncthreads();

    // --- intra-block exclusive scan of nm (Hillis-Steele) ---
    red[tid] = nm;
    __syncthreads();
    for (int off = 1; off < 256; off <<= 1) {
        int x = (tid >= off) ? red[tid - off] : 0;
        __syncthreads();
        red[tid] += x;
        __syncthreads();
    }
    int base = bb + red[tid] - nm;

    if (i < N) {
        int p = (i << 8);
        for (int n = 1; n <= nm; n++) {
            int m = base + n - 1;
            if (m >= M) break;               // m increases with n
            pack[m] = p | n;
        }
    }
}

// K3 (fused): blocks [0,gs) do per-entry scalar outputs (hkl/dHKL/wl),
//             blocks [gs,..) do the meta float4 gather-scatter.
__global__ void k_out(const int* __restrict__ pack, const int* __restrict__ hkl,
                      const float* __restrict__ dHKL, const float* __restrict__ wl,
                      const float* __restrict__ meta, float* __restrict__ out,
                      int M, int N, int gs,
                      int total, int pad, int nbody4, int nextra) {
    if ((int)blockIdx.x < gs) {
        // ---- scalar part: one entry per thread, hkl staged via LDS ----
        __shared__ float sh[768];
        int m0 = blockIdx.x * 256;
        int m = m0 + threadIdx.x;
        int mm = (m < M) ? m : (M - 1);
        int p = pack[mm];
        int row = p >> 8;
        int n = p & 255;
        if (row >= N || row < 0 || n == 0) { row = 0; n = 1; }   // poison safety
        int h = hkl[3 * row], k = hkl[3 * row + 1], l = hkl[3 * row + 2];
        int g = gcd3(h, k, l);
        if (g < 1) g = 1;
        float gf = (float)g;
        float nf = (float)n;
        sh[3 * threadIdx.x]     = (float)((h / g) * n);
        sh[3 * threadIdx.x + 1] = (float)((k / g) * n);
        sh[3 * threadIdx.x + 2] = (float)((l / g) * n);
        if (m < M) {
            __builtin_nontemporal_store((dHKL[row] * gf) / nf, &out[(size_t)3 * M + m]);
            __builtin_nontemporal_store((wl[row] * gf) / nf,   &out[(size_t)4 * M + m]);
        }
        __syncthreads();
        // unit-stride coalesced store of the 768-dword hkl tile
        int ob = 3 * m0;
        for (int j = (int)threadIdx.x; j < 768; j += 256) {
            int idx = ob + j;
            if (idx < 3 * M) __builtin_nontemporal_store(sh[j], &out[idx]);
        }
    } else {
        // ---- meta part: one aligned float4 store per body thread ----
        float* __restrict__ out5 = out + (size_t)5 * M;
        int t = ((int)blockIdx.x - gs) * 256 + threadIdx.x;
        if (t < nbody4) {
            int p = pad + (t << 2);
            int m0 = p >> 5;
            int ra = pack[m0] >> 8;
            if (ra >= N || ra < 0) ra = 0;               // poison safety
            f32x4 v;
            int c = p & 31;                              // dword offset in row
            if (pad == 0) {
                // c % 4 == 0: aligned 16B load, never crosses a row
                const f32x4* meta4 = (const f32x4*)meta;
                v = meta4[(ra << 3) + (c >> 2)];
            } else if (c <= 28) {
                // intra-row group: single (dword-aligned) 16B vector load
                __builtin_memcpy(&v, meta + ((size_t)ra << 5) + c, 16);
            } else {
                // straddles row boundary: dual-row scalar path (verified)
                int m3 = (p + 3) >> 5;
                int rb = (m3 == m0) ? ra : (pack[m3] >> 8);
                if (rb >= N || rb < 0) rb = 0;
                {
                    int pj = p;     int mj = pj >> 5; int rj = (mj == m0) ? ra : rb;
                    v.x = meta[(rj << 5) + (pj & 31)];
                }
                {
                    int pj = p + 1; int mj = pj >> 5; int rj = (mj == m0) ? ra : rb;
                    v.y = meta[(rj << 5) + (pj & 31)];
                }
                {
                    int pj = p + 2; int mj = pj >> 5; int rj = (mj == m0) ? ra : rb;
                    v.z = meta[(rj << 5) + (pj & 31)];
                }
                {
                    int pj = p + 3; int mj = pj >> 5; int rj = (mj == m0) ? ra : rb;
                    v.w = meta[(rj << 5) + (pj & 31)];
                }
            }
            // (5M + p) % 4 == 0 by construction of pad -> 16B-aligned store
            __builtin_nontemporal_store(v, (f32x4*)(out5 + p));
        } else {
            int e = t - nbody4;
            if (e < nextra) {
                int p = (e < pad) ? e : (pad + (nbody4 << 2) + (e - pad));
                if (p < total) {
                    int m = p >> 5;
                    int r = pack[m] >> 8;
                    if (r >= N || r < 0) r = 0;
                    __builtin_nontemporal_store(meta[(r << 5) + (p & 31)], out5 + p);
                }
            }
        }
    }
}

extern "C" void kernel_launch(void* const* d_in, const int* in_sizes, int n_in,
                              void* d_out, int out_size, void* d_ws, size_t ws_size,
                              hipStream_t stream) {
    const int*   hkl  = (const int*)d_in[0];
    const float* dHKL = (const float*)d_in[1];
    const float* wl   = (const float*)d_in[2];
    const float* meta = (const float*)d_in[3];
    const float* dmin = (const float*)d_in[4];
    float* out = (float*)d_out;

    int N = in_sizes[0] / 3;
    int M = out_size / 37;
    if (N <= 0 || M <= 0) return;
    int nb = (N + 255) / 256;

    int* bsums = (int*)d_ws;      // [nb]
    int* pack  = bsums + nb;      // [M]

    k_count<<<nb, 256, 0, stream>>>(hkl, dHKL, dmin, bsums, N);
    k_expand<<<nb, 256, 0, stream>>>(hkl, dHKL, dmin, bsums, pack, N, M);

    // fused output kernel: scalar blocks + meta blocks
    int gs = (M + 255) / 256;
    int total = 32 * M;                      // dwords of meta_out
    int base  = 5 * M;                       // dword offset of meta_out in out
    int pad   = (4 - (base & 3)) & 3;
    if (pad > total) pad = total;
    int body   = total - pad;
    int nbody4 = body >> 2;
    int tail   = body & 3;
    int nextra = pad + tail;
    int gm = (nbody4 + nextra + 255) / 256;
    k_out<<<gs + gm, 256, 0, stream>>>(pack, hkl, dHKL, wl, meta, out,
                                       M, N, gs, total, pad, nbody4, nextra);
}